// Round 5
// baseline (198.299 us; speedup 1.0000x reference)
//
#include <hip/hip_runtime.h>

typedef _Float16 f16;
typedef _Float16 f16x2 __attribute__((ext_vector_type(2)));
typedef _Float16 f16x8 __attribute__((ext_vector_type(8)));
typedef float    f32x16 __attribute__((ext_vector_type(16)));

#define DIM 128

// silu(x) = x / (1 + e^-x); v_exp_f32 is 2^x so scale by log2(e). v_rcp_f32 ~1ulp.
__device__ __forceinline__ float silu_f(float x) {
    float e = __builtin_amdgcn_exp2f(x * -1.44269504088896341f);
    return x * __builtin_amdgcn_rcpf(1.0f + e);
}

// Barrier-free M-split on 32x32x16 MFMA: block = 512 threads = 8 waves, each wave
// owns 32 rows end-to-end (block-tile = 256 rows). Weights in LDS B-frags (64 KB
// shared); x1 WAVE-PRIVATE (8 KB/wave, XOR-swizzled) -> zero main-loop barriers.
// r5 changes (attack the per-iteration global-memory wait chain):
//  (1) epilogue-2 repacks C-frags through the wave-private LDS slab (reusing x1p;
//      same-wave DS ops are in-order) and stores with 16 global_store_dwordx4 per
//      iteration -- two full 512-B row bursts per instruction, 4x fewer vmcnt
//      entries than 64 scattered dword stores.
//  (2) t values are loaded 4 tiles ahead in one batch and rotated through
//      registers -> no load-use vmcnt wait inside the 4-iteration group.
__global__ __launch_bounds__(512, 2)
void ts_mlp_kernel(const float* __restrict__ t,
                   const float* __restrict__ W1, const float* __restrict__ b1,
                   const float* __restrict__ W2, const float* __restrict__ b2,
                   float* __restrict__ out, int B) {
    // B-frag (32x32x16): frag (kt, nt) in lane L holds W[n][k] with
    //   n = nt*32 + (L&31), k = kt*16 + (L>>5)*8 + j, j=0..7
    __shared__ f16x8 w1f[8][4][64];     // 32 KB
    __shared__ f16x8 w2f[8][4][64];     // 32 KB
    // x1 per wave: 32 rows x 128 cols f16 as 16B chunks; chunk (row, c=col>>3) at
    // physical row*16 + (c ^ (row&15)). Also reused per-iteration as a 16x128 f32
    // slab (8 KB) for the output repack (same-wave DS in-order => safe).
    __shared__ f16x2 x1p[8][512][4];    // 64 KB

    const int tid  = threadIdx.x;
    const int wv   = tid >> 6;
    const int lane = tid & 63;
    const int h    = lane >> 5;    // half-wave index (k-group for A/B frags)
    const int l31  = lane & 31;
    const int par  = lane & 1;

    // ---- prologue: wave wv stages k-tile kt=wv of both matrices -> LDS B-frags
    {
        const int kt = wv;
        const int k0 = kt * 16 + h * 8;
#pragma unroll
        for (int mtx = 0; mtx < 2; ++mtx) {
            const float* W = mtx ? W2 : W1;
#pragma unroll
            for (int nt = 0; nt < 4; ++nt) {
                const int n = nt * 32 + l31;
                const float4* src = (const float4*)(W + n * DIM + k0);
                float4 lo = src[0], hi = src[1];
                f16x8 fr;
                fr[0] = (f16)lo.x; fr[1] = (f16)lo.y; fr[2] = (f16)lo.z; fr[3] = (f16)lo.w;
                fr[4] = (f16)hi.x; fr[5] = (f16)hi.y; fr[6] = (f16)hi.z; fr[7] = (f16)hi.w;
                if (mtx) w2f[kt][nt][lane] = fr; else w1f[kt][nt][lane] = fr;
            }
        }
    }
    float b1v[4], b2v[4];
#pragma unroll
    for (int nt = 0; nt < 4; ++nt) {
        b1v[nt] = b1[nt * 32 + l31];
        b2v[nt] = b2[nt * 32 + l31];
    }
    float* const slab = reinterpret_cast<float*>(&x1p[wv][0][0]);
    __syncthreads();   // the ONLY barrier in the kernel

    const int ntiles = B >> 8;            // 256 rows per block-tile
    const int stride = gridDim.x;
    const float h8f = (float)(h * 8);
    const int toff = wv * 32 + l31;

    for (int base = blockIdx.x; base < ntiles; base += stride * 4) {
        // batch-load 4 t values (one per upcoming tile); rotated through registers
        float t4_0 = t[base * 256 + toff];
        float t4_1 = (base + stride     < ntiles) ? t[(base + stride)     * 256 + toff] : 0.f;
        float t4_2 = (base + stride * 2 < ntiles) ? t[(base + stride * 2) * 256 + toff] : 0.f;
        float t4_3 = (base + stride * 3 < ntiles) ? t[(base + stride * 3) * 256 + toff] : 0.f;

#pragma unroll 1
        for (int i = 0; i < 4; ++i) {
            const int tile = base + i * stride;
            if (tile >= ntiles) break;
            const float tv = t4_0;
            t4_0 = t4_1; t4_1 = t4_2; t4_2 = t4_3;
            const int row0 = tile * 256 + wv * 32;

            // ---- emb directly in 32x32 A-frag layout: row m = l31, k = kt*16+h*8+j
            // v_sin/v_cos take REVOLUTIONS: phase_d * t / 2pi = d*t/256
            const float t256 = tv * 0.00390625f;
            const float o256 = (1.0f - tv) * 0.00390625f;
            f16x8 af[8];
#pragma unroll
            for (int kt = 0; kt < 8; ++kt) {
#pragma unroll
                for (int j = 0; j < 8; ++j) {
                    const float fd = (float)(kt * 16 + j) + h8f;
                    const float c  = __builtin_amdgcn_cosf(fd * t256);
                    const float s  = __builtin_amdgcn_sinf(fd * o256);
                    af[kt][j] = (f16)(tv * (c + s));
                }
            }

            // ---- layer 1: 32 MFMAs (32x32x16), B-frags from shared LDS
            f32x16 acc[4];
#pragma unroll
            for (int nt = 0; nt < 4; ++nt)
#pragma unroll
                for (int r = 0; r < 16; ++r) acc[nt][r] = 0.0f;
#pragma unroll
            for (int kt = 0; kt < 8; ++kt) {
#pragma unroll
                for (int nt = 0; nt < 4; ++nt) {
                    acc[nt] = __builtin_amdgcn_mfma_f32_32x32x16_f16(
                        af[kt], w1f[kt][nt][lane], acc[nt], 0, 0, 0);
                }
            }

            // ---- epilogue 1: bias + silu, pack col-pairs cross-lane, write x1 fp16
            // C layout: reg r in lane L is x1[row=(r&3)+8*(r>>2)+4*h][col=nt*32+l31]
#pragma unroll
            for (int nt = 0; nt < 4; ++nt) {
                float v[16], pv[16];
#pragma unroll
                for (int r = 0; r < 16; ++r) v[r] = silu_f(acc[nt][r] + b1v[nt]);
#pragma unroll
                for (int r = 0; r < 16; ++r) pv[r] = __shfl_xor(v[r], 1, 64);
                const int cch = nt * 4 + ((lane & 30) >> 3);   // 16B chunk index
                const int dw  = (lane & 6) >> 1;               // dword within chunk
#pragma unroll
                for (int w8 = 0; w8 < 8; ++w8) {
                    const int r   = par * 8 + w8;   // even lanes r=0..7, odd r=8..15
                    const int row = (r & 3) + 8 * (r >> 2) + 4 * h;
                    const float lo = par ? pv[r] : v[r];
                    const float hi = par ? v[r] : pv[r];
                    f16x2 hh; hh.x = (f16)lo; hh.y = (f16)hi;
                    x1p[wv][row * 16 + (cch ^ (row & 15))][dw] = hh;
                }
            }
            // x1p slice is wave-private; same-wave DS ops are in-order -> no barrier.

            // ---- layer 2: A-frags from swizzled x1 (8 ds_read_b128), 32 MFMAs
            f32x16 acc2[4];
#pragma unroll
            for (int nt = 0; nt < 4; ++nt)
#pragma unroll
                for (int r = 0; r < 16; ++r) acc2[nt][r] = 0.0f;
#pragma unroll
            for (int kt = 0; kt < 8; ++kt) {
                // row = l31, chunk c = kt*2 + h; physical = l31*16 + (c ^ (l31&15))
                const f16x8 a2 = *(const f16x8*)&x1p[wv][l31 * 16 + ((kt * 2 + h) ^ (l31 & 15))][0];
#pragma unroll
                for (int nt = 0; nt < 4; ++nt) {
                    acc2[nt] = __builtin_amdgcn_mfma_f32_32x32x16_f16(
                        a2, w2f[kt][nt][lane], acc2[nt], 0, 0, 0);
                }
            }

            // ---- epilogue 2: bias + silu, repack via wave-private LDS slab, then
            // 16 global_store_dwordx4: each instr = rows (2i+h), 512 B contiguous.
            // slab reuse is safe: l2's x1 reads precede these writes in program
            // order and same-wave DS ops execute in order.
#pragma unroll
            for (int round = 0; round < 2; ++round) {
#pragma unroll
                for (int nt = 0; nt < 4; ++nt) {
#pragma unroll
                    for (int rr = 0; rr < 8; ++rr) {
                        const int R  = round * 8 + rr;
                        const int rl = (rr & 3) + 8 * (rr >> 2) + 4 * h;  // 0..15
                        const float o = silu_f(acc2[nt][R] + b2v[nt]);
                        slab[rl * 128 + nt * 32 + l31] = o;   // banks 0..31, free
                    }
                }
#pragma unroll
                for (int i8 = 0; i8 < 8; ++i8) {
                    const int rl = 2 * i8 + h;
                    const float4 v4 = *(const float4*)&slab[rl * 128 + l31 * 4];
                    *(float4*)&out[(size_t)(row0 + round * 16 + rl) * DIM + l31 * 4] = v4;
                }
            }
        }
    }
}

extern "C" void kernel_launch(void* const* d_in, const int* in_sizes, int n_in,
                              void* d_out, int out_size, void* d_ws, size_t ws_size,
                              hipStream_t stream) {
    const float* t  = (const float*)d_in[0];
    const float* W1 = (const float*)d_in[1];
    const float* b1 = (const float*)d_in[2];
    const float* W2 = (const float*)d_in[3];
    const float* b2 = (const float*)d_in[4];
    float* out = (float*)d_out;
    const int B = in_sizes[0];
    const int ntiles = B >> 8;              // 256 rows per block-tile
    // 1 block/CU (128 KB LDS); 256 blocks x 4 tiles each, perfectly balanced
    int grid = ntiles < 256 ? ntiles : 256;
    ts_mlp_kernel<<<dim3(grid), dim3(512), 0, stream>>>(t, W1, b1, W2, b2, out, B);
}